// Round 12
// baseline (347.074 us; speedup 1.0000x reference)
//
#include <hip/hip_runtime.h>
#include <hip/hip_bf16.h>

#define DIN  128
#define DHID 128
#define DOUT 64

#define EB   4096   // edges per fill block
#define CAPB 5120   // fixed edge capacity per 256-node bucket (mean 4096, 16 sigma)

typedef short short8 __attribute__((ext_vector_type(8)));
typedef float f32x4  __attribute__((ext_vector_type(4)));

__device__ __forceinline__ ushort f2bf(float f) {
    union { float f; uint u; } c; c.f = f;
    uint u = c.u;
    return (ushort)((u + 0x7fff + ((u >> 16) & 1)) >> 16);   // RNE
}
__device__ __forceinline__ float bf2f(uint h16) {
    union { uint u; float f; } c; c.u = h16 << 16;
    return c.f;
}
// signed byte k of packed uint -> float
__device__ __forceinline__ float sb8(uint u, int k) {
    return (float)((int)(u << (24 - 8 * k)) >> 24);
}

// ---------------------------------------------------------------------------
// Mega-prep: [bucket_fill | cvt_bf16 | 6x weight transpose] in ONE dispatch.
// ---------------------------------------------------------------------------
__device__ __forceinline__ void wprep_dev(const float* __restrict__ W,
                                          ushort* __restrict__ Wt, int OUT, int idx) {
    int nn = idx >> 7;
    int k  = idx & 127;
    Wt[idx] = f2bf(W[(size_t)k * OUT + nn]);   // Wt[n][k] = W[k][n]
}

__global__ __launch_bounds__(256)
void megaprep(const int* __restrict__ src, const int* __restrict__ dst, int E, int fillB,
              int* __restrict__ bkt_cur, uint* __restrict__ pairs,
              const float* __restrict__ x, ushort* __restrict__ xb, int n4, int cvtB,
              const float* __restrict__ Ws1, const float* __restrict__ Wn1,
              const float* __restrict__ Ws2, const float* __restrict__ Wn2,
              const float* __restrict__ Ws3, const float* __restrict__ Wn3,
              ushort* __restrict__ Wst1, ushort* __restrict__ Wnt1,
              ushort* __restrict__ Wst2, ushort* __restrict__ Wnt2,
              ushort* __restrict__ Wst3, ushort* __restrict__ Wnt3) {
    __shared__ int c[256];
    __shared__ int startl[256];
    __shared__ int ofs[256];
    int b = blockIdx.x;
    const int t = threadIdx.x;
    if (b < fillB) {
        c[t] = 0;
        __syncthreads();
        const int base = b * EB;
        const int end = min(base + EB, E);
        for (int i = base + t; i < end; i += 256)
            atomicAdd(&c[dst[i] >> 8], 1);
        __syncthreads();
        int v = c[t];
        startl[t] = v ? (t * CAPB + atomicAdd(&bkt_cur[t], v)) : 0;
        ofs[t] = 0;
        __syncthreads();
        for (int i = base + t; i < end; i += 256) {
            int d = dst[i];
            int bb = d >> 8;
            int p = startl[bb] + atomicAdd(&ofs[bb], 1);
            pairs[p] = ((uint)src[i] << 8) | (uint)(d & 255);
        }
        return;
    }
    b -= fillB;
    if (b < cvtB) {
        int i = b * 256 + t;
        if (i < n4) {
            float4 v = ((const float4*)x)[i];
            ushort4 o;
            o.x = f2bf(v.x); o.y = f2bf(v.y); o.z = f2bf(v.z); o.w = f2bf(v.w);
            ((ushort4*)xb)[i] = o;
        }
        return;
    }
    b -= cvtB;
    if (b < 64)  { wprep_dev(Ws1, Wst1, 128, b * 256 + t); return; }
    b -= 64;
    if (b < 64)  { wprep_dev(Wn1, Wnt1, 128, b * 256 + t); return; }
    b -= 64;
    if (b < 64)  { wprep_dev(Ws2, Wst2, 128, b * 256 + t); return; }
    b -= 64;
    if (b < 64)  { wprep_dev(Wn2, Wnt2, 128, b * 256 + t); return; }
    b -= 64;
    if (b < 32)  { wprep_dev(Ws3, Wst3, 64, b * 256 + t); return; }
    b -= 32;
    wprep_dev(Wn3, Wnt3, 64, b * 256 + t);
}

// ---------------------------------------------------------------------------
// bucket_csr: one block per bucket -> row_ptr + deg + contiguous esrc.
// ---------------------------------------------------------------------------
__global__ __launch_bounds__(256)
void bucket_csr(const uint* __restrict__ pairs, const int* __restrict__ bkt_cur,
                int* __restrict__ row_ptr, int* __restrict__ deg,
                int* __restrict__ esrc, int N, int nbkt) {
    constexpr int CAP = 6144;
    __shared__ uint pl[CAP];
    __shared__ int cnt[256];
    __shared__ int rs[256];
    __shared__ int sc[256];
    const int bkt = blockIdx.x;
    const int t = threadIdx.x;
    const int ebase = bkt * CAPB;
    const int ecnt  = min(bkt_cur[bkt], CAPB);
    cnt[t] = 0;
    __syncthreads();
    for (int i = t; i < ecnt; i += 256) {
        uint p = pairs[ebase + i];
        pl[i] = p;
        atomicAdd(&cnt[p & 255u], 1);
    }
    __syncthreads();
    int own = cnt[t];
    sc[t] = own;
    __syncthreads();
    for (int o = 1; o < 256; o <<= 1) {
        int u = (t >= o) ? sc[t - o] : 0;
        __syncthreads();
        sc[t] += u;
        __syncthreads();
    }
    rs[t] = sc[t] - own;
    const int node = bkt * 256 + t;
    if (node < N) {
        row_ptr[node] = ebase + rs[t];
        deg[node] = own;
    }
    __syncthreads();
    for (int i = t; i < ecnt; i += 256) {
        uint p = pl[i];
        int pos = atomicAdd(&rs[p & 255u], 1);
        esrc[ebase + pos] = (int)(p >> 8);
    }
}

// ---------------------------------------------------------------------------
// G-GEMM: G = H @ Wn -> int8 + per-row scale. Block = 256 thr = 4 waves,
// 64 rows (wave = 16 rows x OUTW cols); Wn staged in LDS once per block.
// ---------------------------------------------------------------------------
template<int OUTW>
__global__ __launch_bounds__(256)
void gemm_G(const ushort* __restrict__ Hb,      // [n][128] bf16
            const ushort* __restrict__ Wnt,     // [OUTW][128] bf16
            signed char* __restrict__ Gq,       // [n][OUTW] int8
            float* __restrict__ Gsc,            // [n] fp32
            int n) {
    constexpr int NT = OUTW / 16;               // 8 or 4
    __shared__ ushort Wl[OUTW * 128];

    const int tid  = threadIdx.x;
    const int lane = tid & 63;
    const int wave = tid >> 6;                  // 0..3
    const int m16  = lane & 15;
    const int kb   = lane >> 4;                 // 0..3
    const int rbase = blockIdx.x * 64 + wave * 16;

    {
        const uint4* n4 = (const uint4*)Wnt;
        uint4* ln = (uint4*)&Wl[0];
#pragma unroll
        for (int j = tid; j < OUTW * 128 / 8; j += 256)
            ln[j] = n4[j];
    }

    short8 a[4];
    {
        int arow = rbase + m16; if (arow >= n) arow = n - 1;
        const ushort* __restrict__ Ap = &Hb[(size_t)arow * 128 + kb * 8];
#pragma unroll
        for (int c = 0; c < 4; ++c)
            a[c] = *(const short8*)(Ap + c * 32);
    }

    __syncthreads();

    f32x4 acc[NT];
#pragma unroll
    for (int t = 0; t < NT; ++t) acc[t] = (f32x4)(0.f);

#pragma unroll
    for (int t = 0; t < NT; ++t) {
#pragma unroll
        for (int c = 0; c < 4; ++c) {
            short8 b = *(const short8*)&Wl[(t * 16 + m16) * 128 + c * 32 + kb * 8];
            acc[t] = __builtin_amdgcn_mfma_f32_16x16x32_bf16(a[c], b, acc[t], 0, 0, 0);
        }
    }

    // D layout: col = t*16 + m16, row = kb*4 + r
#pragma unroll
    for (int r = 0; r < 4; ++r) {
        float mx = 0.f;
#pragma unroll
        for (int t = 0; t < NT; ++t) mx = fmaxf(mx, fabsf(acc[t][r]));
        mx = fmaxf(mx, __shfl_xor(mx, 1));
        mx = fmaxf(mx, __shfl_xor(mx, 2));
        mx = fmaxf(mx, __shfl_xor(mx, 4));
        mx = fmaxf(mx, __shfl_xor(mx, 8));      // 16-lane row max
        int row = rbase + kb * 4 + r;
        if (row >= n) continue;
        float inv = (mx > 0.f) ? 127.f / mx : 0.f;
        if (m16 == 0) Gsc[row] = mx * (1.f / 127.f);
#pragma unroll
        for (int t = 0; t < NT; ++t) {
            int q = (int)rintf(acc[t][r] * inv);
            q = max(-127, min(127, q));
            Gq[(size_t)row * OUTW + t * 16 + m16] = (signed char)q;
        }
    }
}

// ---------------------------------------------------------------------------
// Fused gather + S-GEMM: per block of 32 nodes,
//   (1) stage Ws in LDS + edge indices/scales in LDS,
//   (2) MFMA the block's own 32xOUTW S = H@Ws tile into LDS (fp32, never
//       touches global),
//   (3) gather-mean int8 G rows, epilogue z = S_lds + mean + b (relu*mask).
// ---------------------------------------------------------------------------
__device__ __forceinline__ void acc8(float* af, uint2 v, float sc) {
    af[0] += sc * sb8(v.x, 0); af[1] += sc * sb8(v.x, 1);
    af[2] += sc * sb8(v.x, 2); af[3] += sc * sb8(v.x, 3);
    af[4] += sc * sb8(v.y, 0); af[5] += sc * sb8(v.y, 1);
    af[6] += sc * sb8(v.y, 2); af[7] += sc * sb8(v.y, 3);
}
__device__ __forceinline__ void acc4(float* af, uint v, float sc) {
    af[0] += sc * sb8(v, 0); af[1] += sc * sb8(v, 1);
    af[2] += sc * sb8(v, 2); af[3] += sc * sb8(v, 3);
}

#define SPAN_CAP 1024

template<bool FINAL>
__global__ __launch_bounds__(256)
void gather_S(const ushort* __restrict__ Hb,    // [n][128] bf16 (own rows for S)
              const ushort* __restrict__ Wst,   // [OUTW][128] bf16
              const signed char* __restrict__ Gq, const float* __restrict__ Gsc,
              const float* __restrict__ bias, const float* __restrict__ mask,
              const int* __restrict__ row_ptr, const int* __restrict__ deg,
              const int* __restrict__ esrc,
              void* __restrict__ outv, int n) {
    constexpr int OUTW = FINAL ? 64 : 128;
    constexpr int SP   = OUTW + 4;              // padded S row (floats)
    __shared__ ushort Wl[OUTW * 128];
    __shared__ float  Sl[32 * SP];
    __shared__ int    idx_s[SPAN_CAP];
    __shared__ float  sc_s[SPAN_CAP];

    const int tid  = threadIdx.x;
    const int lane = tid & 63;
    const int wave = tid >> 6;     // 0..3
    const int qw   = lane >> 4;
    const int l16  = lane & 15;
    const int base = blockIdx.x * 32;
    const int m16  = l16;
    const int kb   = qw;           // 0..3

    // --- A fragments for the S-tile (own rows), issued early ---
    const int mt = wave & 1;       // m-tile (16 rows)
    const int nq = wave >> 1;      // col group
    short8 a[4];
    {
        int arow = base + mt * 16 + m16; if (arow >= n) arow = n - 1;
        const ushort* __restrict__ Ap = &Hb[(size_t)arow * 128 + kb * 8];
#pragma unroll
        for (int c = 0; c < 4; ++c)
            a[c] = *(const short8*)(Ap + c * 32);
    }

    // --- Stage Ws ---
    {
        const uint4* s4 = (const uint4*)Wst;
        uint4* ls = (uint4*)&Wl[0];
#pragma unroll
        for (int j = tid; j < OUTW * 128 / 8; j += 256)
            ls[j] = s4[j];
    }

    // --- Stage edge span (indices + scales) ---
    const int last   = min(base + 31, n - 1);
    const int span_s = row_ptr[base];
    const int span_e = row_ptr[last] + deg[last];
    const int len    = span_e - span_s;
    const bool staged = (len <= SPAN_CAP);
    if (staged) {
        for (int i = tid; i < len; i += 256) {
            int s_ = esrc[span_s + i];
            idx_s[i] = s_;
            sc_s[i] = Gsc[s_];
        }
    }
    __syncthreads();

    // --- S-tile MFMA into LDS ---
    {
        constexpr int TPW = FINAL ? 2 : 4;      // n-tiles per wave
        f32x4 acc[TPW];
#pragma unroll
        for (int t = 0; t < TPW; ++t) acc[t] = (f32x4)(0.f);
#pragma unroll
        for (int t = 0; t < TPW; ++t) {
#pragma unroll
            for (int c = 0; c < 4; ++c) {
                short8 b = *(const short8*)&Wl[(nq * TPW * 16 + t * 16 + m16) * 128 + c * 32 + kb * 8];
                acc[t] = __builtin_amdgcn_mfma_f32_16x16x32_bf16(a[c], b, acc[t], 0, 0, 0);
            }
        }
        // D layout: col = nq*TPW*16 + t*16 + m16, row = kb*4 + r (within m-tile)
#pragma unroll
        for (int t = 0; t < TPW; ++t)
#pragma unroll
            for (int r = 0; r < 4; ++r)
                Sl[(mt * 16 + kb * 4 + r) * SP + nq * TPW * 16 + t * 16 + m16] = acc[t][r];
    }
    __syncthreads();

    // --- Gather + epilogue ---
#pragma unroll
    for (int j = 0; j < 2; ++j) {
        const int node = base + (wave * 4 + qw) * 2 + j;
        if (node >= n) continue;
        const int ln = node - base;
        const int d = deg[node];
        const float inv = 1.f / fmaxf((float)d, 1.f);

        if (!FINAL) {
            float af[8] = {0.f, 0.f, 0.f, 0.f, 0.f, 0.f, 0.f, 0.f};
            const signed char* __restrict__ gp = Gq + l16 * 8;
            if (staged) {
                int i = row_ptr[node] - span_s, e = i + d;
                for (; i + 7 < e; i += 8) {
                    uint2 v[8]; float c[8];
#pragma unroll
                    for (int k = 0; k < 8; ++k) {
                        int ns = idx_s[i + k];
                        v[k] = *(const uint2*)&gp[(size_t)ns * 128];
                        c[k] = sc_s[i + k];
                    }
#pragma unroll
                    for (int k = 0; k < 8; ++k) acc8(af, v[k], c[k]);
                }
                for (; i < e; ++i) {
                    int ns = idx_s[i];
                    acc8(af, *(const uint2*)&gp[(size_t)ns * 128], sc_s[i]);
                }
            } else {
                int i = row_ptr[node], e = i + d;
                for (; i < e; ++i) {
                    int ns = esrc[i];
                    acc8(af, *(const uint2*)&gp[(size_t)ns * 128], Gsc[ns]);
                }
            }
            const int col0 = l16 * 8;
            float4 s0 = *(const float4*)&Sl[ln * SP + col0];
            float4 s1 = *(const float4*)&Sl[ln * SP + col0 + 4];
            float4 b0 = *(const float4*)&bias[col0];
            float4 b1 = *(const float4*)&bias[col0 + 4];
            float z[8];
            z[0] = s0.x + af[0] * inv + b0.x;
            z[1] = s0.y + af[1] * inv + b0.y;
            z[2] = s0.z + af[2] * inv + b0.z;
            z[3] = s0.w + af[3] * inv + b0.w;
            z[4] = s1.x + af[4] * inv + b1.x;
            z[5] = s1.y + af[5] * inv + b1.y;
            z[6] = s1.z + af[6] * inv + b1.z;
            z[7] = s1.w + af[7] * inv + b1.w;
            float4 m0 = *(const float4*)&mask[(size_t)node * 128 + col0];
            float4 m1 = *(const float4*)&mask[(size_t)node * 128 + col0 + 4];
            z[0] = fmaxf(z[0], 0.f) * m0.x; z[1] = fmaxf(z[1], 0.f) * m0.y;
            z[2] = fmaxf(z[2], 0.f) * m0.z; z[3] = fmaxf(z[3], 0.f) * m0.w;
            z[4] = fmaxf(z[4], 0.f) * m1.x; z[5] = fmaxf(z[5], 0.f) * m1.y;
            z[6] = fmaxf(z[6], 0.f) * m1.z; z[7] = fmaxf(z[7], 0.f) * m1.w;
            uint4 pk;
            pk.x = (uint)f2bf(z[0]) | ((uint)f2bf(z[1]) << 16);
            pk.y = (uint)f2bf(z[2]) | ((uint)f2bf(z[3]) << 16);
            pk.z = (uint)f2bf(z[4]) | ((uint)f2bf(z[5]) << 16);
            pk.w = (uint)f2bf(z[6]) | ((uint)f2bf(z[7]) << 16);
            *(uint4*)&((ushort*)outv)[(size_t)node * 128 + col0] = pk;
        } else {
            float af[4] = {0.f, 0.f, 0.f, 0.f};
            const signed char* __restrict__ gp = Gq + l16 * 4;
            if (staged) {
                int i = row_ptr[node] - span_s, e = i + d;
                for (; i + 7 < e; i += 8) {
                    uint v[8]; float c[8];
#pragma unroll
                    for (int k = 0; k < 8; ++k) {
                        int ns = idx_s[i + k];
                        v[k] = *(const uint*)&gp[(size_t)ns * 64];
                        c[k] = sc_s[i + k];
                    }
#pragma unroll
                    for (int k = 0; k < 8; ++k) acc4(af, v[k], c[k]);
                }
                for (; i < e; ++i) {
                    int ns = idx_s[i];
                    acc4(af, *(const uint*)&gp[(size_t)ns * 64], sc_s[i]);
                }
            } else {
                int i = row_ptr[node], e = i + d;
                for (; i < e; ++i) {
                    int ns = esrc[i];
                    acc4(af, *(const uint*)&gp[(size_t)ns * 64], Gsc[ns]);
                }
            }
            const int col0 = l16 * 4;
            float4 s0 = *(const float4*)&Sl[ln * SP + col0];
            float4 b0 = *(const float4*)&bias[col0];
            float4 z;
            z.x = s0.x + af[0] * inv + b0.x;
            z.y = s0.y + af[1] * inv + b0.y;
            z.z = s0.z + af[2] * inv + b0.z;
            z.w = s0.w + af[3] * inv + b0.w;
            *(float4*)&((float*)outv)[(size_t)node * 64 + col0] = z;
        }
    }
}

// ---------------------------------------------------------------------------
extern "C" void kernel_launch(void* const* d_in, const int* in_sizes, int n_in,
                              void* d_out, int out_size, void* d_ws, size_t ws_size,
                              hipStream_t stream) {
    const float* x   = (const float*)d_in[0];
    const int*   src = (const int*)d_in[1];
    const int*   dst = (const int*)d_in[2];
    const float* Ws1 = (const float*)d_in[3];
    const float* Wn1 = (const float*)d_in[4];
    const float* b1  = (const float*)d_in[5];
    const float* Ws2 = (const float*)d_in[6];
    const float* Wn2 = (const float*)d_in[7];
    const float* b2  = (const float*)d_in[8];
    const float* Ws3 = (const float*)d_in[9];
    const float* Wn3 = (const float*)d_in[10];
    const float* b3  = (const float*)d_in[11];
    const float* mask1 = (const float*)d_in[12];
    const float* mask2 = (const float*)d_in[13];
    float* out = (float*)d_out;

    const int N = in_sizes[0] / DIN;
    const int E = in_sizes[1];
    const int nbkt = (N + 255) >> 8;            // 196 for N=50000 (<=256)

    // Workspace layout
    char* ws = (char*)d_ws;
    int* bkt_cur  = (int*)ws;                   // 256
    int* row_ptr  = bkt_cur + 256;              // N
    int* deg      = row_ptr + N;                // N
    int* esrc     = deg + N;                    // nbkt*CAPB
    size_t off = ((size_t)(256 + 2 * N + nbkt * CAPB) * sizeof(int) + 255) & ~(size_t)255;
    uint* pairs  = (uint*)(ws + off);    off += (size_t)nbkt * CAPB * 4;
    ushort* xb   = (ushort*)(ws + off);  off += (size_t)N * 128 * 2;
    ushort* h1b  = (ushort*)(ws + off);  off += (size_t)N * 128 * 2;
    ushort* h2b  = (ushort*)(ws + off);  off += (size_t)N * 128 * 2;
    signed char* Gq = (signed char*)(ws + off); off += (size_t)N * 128;
    float* Gsc   = (float*)(ws + off);   off += (size_t)N * 4;
    ushort* Wst1 = (ushort*)(ws + off);  off += 128 * 128 * 2;
    ushort* Wnt1 = (ushort*)(ws + off);  off += 128 * 128 * 2;
    ushort* Wst2 = (ushort*)(ws + off);  off += 128 * 128 * 2;
    ushort* Wnt2 = (ushort*)(ws + off);  off += 128 * 128 * 2;
    ushort* Wst3 = (ushort*)(ws + off);  off += 64 * 128 * 2;
    ushort* Wnt3 = (ushort*)(ws + off);  off += 64 * 128 * 2;

    const int n4 = N * 128 / 4;
    const int cvtB = (n4 + 255) / 256;
    const int fillB = (E + EB - 1) / EB;

    // --- One prep dispatch: bucket fill + cvt + weight transposes ---
    hipMemsetAsync(bkt_cur, 0, 256 * sizeof(int), stream);
    megaprep<<<fillB + cvtB + 4 * 64 + 2 * 32, 256, 0, stream>>>(
        src, dst, E, fillB, bkt_cur, pairs,
        x, xb, n4, cvtB,
        Ws1, Wn1, Ws2, Wn2, Ws3, Wn3,
        Wst1, Wnt1, Wst2, Wnt2, Wst3, Wnt3);

    // --- CSR within buckets ---
    bucket_csr<<<nbkt, 256, 0, stream>>>(pairs, bkt_cur, row_ptr, deg, esrc, N, nbkt);

    const int gemmB = (N + 63) / 64;
    const int gathB = (N + 31) / 32;

    // --- Layer 1 ---
    gemm_G<128><<<gemmB, 256, 0, stream>>>(xb, Wnt1, Gq, Gsc, N);
    gather_S<false><<<gathB, 256, 0, stream>>>(xb, Wst1, Gq, Gsc, b1, mask1, row_ptr, deg, esrc, h1b, N);
    // --- Layer 2 ---
    gemm_G<128><<<gemmB, 256, 0, stream>>>(h1b, Wnt2, Gq, Gsc, N);
    gather_S<false><<<gathB, 256, 0, stream>>>(h1b, Wst2, Gq, Gsc, b2, mask2, row_ptr, deg, esrc, h2b, N);
    // --- Layer 3 ---
    gemm_G<64><<<gemmB, 256, 0, stream>>>(h2b, Wnt3, Gq, Gsc, N);
    gather_S<true><<<gathB, 256, 0, stream>>>(h2b, Wst3, Gq, Gsc, b3, nullptr, row_ptr, deg, esrc, out, N);
}

// Round 13
// 346.386 us; speedup vs baseline: 1.0020x; 1.0020x over previous
//
#include <hip/hip_runtime.h>
#include <hip/hip_bf16.h>

#define DIN  128
#define DHID 128
#define DOUT 64

#define EB   16384  // edges per fill block (long per-bucket runs -> low write amp)
#define CAPB 5120   // fixed edge capacity per 256-node bucket (mean 4096, 16 sigma)

typedef short short8 __attribute__((ext_vector_type(8)));
typedef float f32x4  __attribute__((ext_vector_type(4)));

__device__ __forceinline__ ushort f2bf(float f) {
    union { float f; uint u; } c; c.f = f;
    uint u = c.u;
    return (ushort)((u + 0x7fff + ((u >> 16) & 1)) >> 16);   // RNE
}
__device__ __forceinline__ float bf2f(uint h16) {
    union { uint u; float f; } c; c.u = h16 << 16;
    return c.f;
}
// signed byte k of packed uint -> float
__device__ __forceinline__ float sb8(uint u, int k) {
    return (float)((int)(u << (24 - 8 * k)) >> 24);
}

// ---------------------------------------------------------------------------
// Mega-prep: [bucket_fill | cvt_bf16 | 6x weight transpose] in ONE dispatch.
// ---------------------------------------------------------------------------
__device__ __forceinline__ void wprep_dev(const float* __restrict__ W,
                                          ushort* __restrict__ Wt, int OUT, int idx) {
    int nn = idx >> 7;
    int k  = idx & 127;
    Wt[idx] = f2bf(W[(size_t)k * OUT + nn]);   // Wt[n][k] = W[k][n]
}

__global__ __launch_bounds__(256)
void megaprep(const int* __restrict__ src, const int* __restrict__ dst, int E, int fillB,
              int* __restrict__ bkt_cur, uint* __restrict__ pairs,
              const float* __restrict__ x, ushort* __restrict__ xb, int n4, int cvtB,
              const float* __restrict__ Ws1, const float* __restrict__ Wn1,
              const float* __restrict__ Ws2, const float* __restrict__ Wn2,
              const float* __restrict__ Ws3, const float* __restrict__ Wn3,
              ushort* __restrict__ Wst1, ushort* __restrict__ Wnt1,
              ushort* __restrict__ Wst2, ushort* __restrict__ Wnt2,
              ushort* __restrict__ Wst3, ushort* __restrict__ Wnt3) {
    __shared__ int c[256];
    __shared__ int startl[256];
    __shared__ int ofs[256];
    int b = blockIdx.x;
    const int t = threadIdx.x;
    if (b < fillB) {
        c[t] = 0;
        __syncthreads();
        const int base = b * EB;
        const int end = min(base + EB, E);
        for (int i = base + t; i < end; i += 256)
            atomicAdd(&c[dst[i] >> 8], 1);
        __syncthreads();
        int v = c[t];
        startl[t] = v ? (t * CAPB + atomicAdd(&bkt_cur[t], v)) : 0;
        ofs[t] = 0;
        __syncthreads();
        for (int i = base + t; i < end; i += 256) {
            int d = dst[i];
            int bb = d >> 8;
            int p = startl[bb] + atomicAdd(&ofs[bb], 1);
            pairs[p] = ((uint)src[i] << 8) | (uint)(d & 255);
        }
        return;
    }
    b -= fillB;
    if (b < cvtB) {
        int i = b * 256 + t;
        if (i < n4) {
            float4 v = ((const float4*)x)[i];
            ushort4 o;
            o.x = f2bf(v.x); o.y = f2bf(v.y); o.z = f2bf(v.z); o.w = f2bf(v.w);
            ((ushort4*)xb)[i] = o;
        }
        return;
    }
    b -= cvtB;
    if (b < 64)  { wprep_dev(Ws1, Wst1, 128, b * 256 + t); return; }
    b -= 64;
    if (b < 64)  { wprep_dev(Wn1, Wnt1, 128, b * 256 + t); return; }
    b -= 64;
    if (b < 64)  { wprep_dev(Ws2, Wst2, 128, b * 256 + t); return; }
    b -= 64;
    if (b < 64)  { wprep_dev(Wn2, Wnt2, 128, b * 256 + t); return; }
    b -= 64;
    if (b < 32)  { wprep_dev(Ws3, Wst3, 64, b * 256 + t); return; }
    b -= 32;
    wprep_dev(Wn3, Wnt3, 64, b * 256 + t);
}

// ---------------------------------------------------------------------------
// bucket_csr: one block per bucket -> row_ptr + deg + contiguous esrc.
// ---------------------------------------------------------------------------
__global__ __launch_bounds__(256)
void bucket_csr(const uint* __restrict__ pairs, const int* __restrict__ bkt_cur,
                int* __restrict__ row_ptr, int* __restrict__ deg,
                int* __restrict__ esrc, int N, int nbkt) {
    constexpr int CAP = 6144;
    __shared__ uint pl[CAP];
    __shared__ int cnt[256];
    __shared__ int rs[256];
    __shared__ int sc[256];
    const int bkt = blockIdx.x;
    const int t = threadIdx.x;
    const int ebase = bkt * CAPB;
    const int ecnt  = min(bkt_cur[bkt], CAPB);
    cnt[t] = 0;
    __syncthreads();
    for (int i = t; i < ecnt; i += 256) {
        uint p = pairs[ebase + i];
        pl[i] = p;
        atomicAdd(&cnt[p & 255u], 1);
    }
    __syncthreads();
    int own = cnt[t];
    sc[t] = own;
    __syncthreads();
    for (int o = 1; o < 256; o <<= 1) {
        int u = (t >= o) ? sc[t - o] : 0;
        __syncthreads();
        sc[t] += u;
        __syncthreads();
    }
    rs[t] = sc[t] - own;
    const int node = bkt * 256 + t;
    if (node < N) {
        row_ptr[node] = ebase + rs[t];
        deg[node] = own;
    }
    __syncthreads();
    for (int i = t; i < ecnt; i += 256) {
        uint p = pl[i];
        int pos = atomicAdd(&rs[p & 255u], 1);
        esrc[ebase + pos] = (int)(p >> 8);
    }
}

// ---------------------------------------------------------------------------
// Dense dual GEMM: S = H @ Ws (bf16), G = H @ Wn (int8 + per-row scale).
// Block = 256 thr = 4 waves, 64 rows; Wst+Wnt staged in LDS once per block.
// ---------------------------------------------------------------------------
template<int OUTW>
__global__ __launch_bounds__(256)
void sage_gemm(const ushort* __restrict__ Hb,      // [n][128] bf16
               const ushort* __restrict__ Wst,     // [OUTW][128] bf16
               const ushort* __restrict__ Wnt,     // [OUTW][128] bf16
               ushort* __restrict__ S,             // [n][OUTW] bf16
               signed char* __restrict__ Gq,       // [n][OUTW] int8
               float* __restrict__ Gsc,            // [n] fp32
               int n) {
    constexpr int NT = OUTW / 16;                  // 8 or 4
    __shared__ ushort Wl[2][OUTW * 128];

    const int tid  = threadIdx.x;
    const int lane = tid & 63;
    const int wave = tid >> 6;                     // 0..3
    const int rg   = wave >> 1;                    // 0..1 (32-row group)
    const int isG  = wave & 1;
    const int m16  = lane & 15;
    const int kb   = lane >> 4;                    // 0..3
    const int rbase = blockIdx.x * 64 + rg * 32;

    {
        const uint4* s4 = (const uint4*)Wst;
        const uint4* n4 = (const uint4*)Wnt;
        uint4* ls = (uint4*)&Wl[0][0];
        uint4* ln = (uint4*)&Wl[1][0];
#pragma unroll
        for (int j = tid; j < OUTW * 128 / 8; j += 256) {
            ls[j] = s4[j];
            ln[j] = n4[j];
        }
    }

    short8 a[2][4];
#pragma unroll
    for (int mt = 0; mt < 2; ++mt) {
        int arow = rbase + mt * 16 + m16;
        if (arow >= n) arow = n - 1;
        const ushort* __restrict__ Ap = &Hb[(size_t)arow * 128 + kb * 8];
#pragma unroll
        for (int c = 0; c < 4; ++c)
            a[mt][c] = *(const short8*)(Ap + c * 32);
    }

    __syncthreads();

    f32x4 acc[2][NT];
#pragma unroll
    for (int mt = 0; mt < 2; ++mt)
#pragma unroll
        for (int t = 0; t < NT; ++t) acc[mt][t] = (f32x4)(0.f);

    const ushort* __restrict__ Wp = &Wl[isG][0];
#pragma unroll
    for (int t = 0; t < NT; ++t) {
#pragma unroll
        for (int c = 0; c < 4; ++c) {
            short8 b = *(const short8*)&Wp[(t * 16 + m16) * 128 + c * 32 + kb * 8];
            acc[0][t] = __builtin_amdgcn_mfma_f32_16x16x32_bf16(a[0][c], b, acc[0][t], 0, 0, 0);
            acc[1][t] = __builtin_amdgcn_mfma_f32_16x16x32_bf16(a[1][c], b, acc[1][t], 0, 0, 0);
        }
    }

#pragma unroll
    for (int mt = 0; mt < 2; ++mt) {
        const int rb = rbase + mt * 16;
        if (!isG) {
#pragma unroll
            for (int r = 0; r < 4; ++r) {
                int row = rb + kb * 4 + r;
                if (row >= n) continue;
#pragma unroll
                for (int t = 0; t < NT; ++t)
                    S[(size_t)row * OUTW + t * 16 + m16] = f2bf(acc[mt][t][r]);
            }
        } else {
#pragma unroll
            for (int r = 0; r < 4; ++r) {
                float mx = 0.f;
#pragma unroll
                for (int t = 0; t < NT; ++t) mx = fmaxf(mx, fabsf(acc[mt][t][r]));
                mx = fmaxf(mx, __shfl_xor(mx, 1));
                mx = fmaxf(mx, __shfl_xor(mx, 2));
                mx = fmaxf(mx, __shfl_xor(mx, 4));
                mx = fmaxf(mx, __shfl_xor(mx, 8));   // 16-lane row max
                int row = rb + kb * 4 + r;
                if (row >= n) continue;
                float inv = (mx > 0.f) ? 127.f / mx : 0.f;
                if (m16 == 0) Gsc[row] = mx * (1.f / 127.f);
#pragma unroll
                for (int t = 0; t < NT; ++t) {
                    int q = (int)rintf(acc[mt][t][r] * inv);
                    q = max(-127, min(127, q));
                    Gq[(size_t)row * OUTW + t * 16 + m16] = (signed char)q;
                }
            }
        }
    }
}

// ---------------------------------------------------------------------------
// Gather-mean over int8 G rows. Block's 32 nodes own a contiguous esrc span:
// stage indices + pre-resolved scales in LDS; inner loop issues one VMEM
// request per edge (the 128B row). 8 rows in flight per quarter-wave.
// ---------------------------------------------------------------------------
__device__ __forceinline__ void acc8(float* af, uint2 v, float sc) {
    af[0] += sc * sb8(v.x, 0); af[1] += sc * sb8(v.x, 1);
    af[2] += sc * sb8(v.x, 2); af[3] += sc * sb8(v.x, 3);
    af[4] += sc * sb8(v.y, 0); af[5] += sc * sb8(v.y, 1);
    af[6] += sc * sb8(v.y, 2); af[7] += sc * sb8(v.y, 3);
}
__device__ __forceinline__ void acc4(float* af, uint v, float sc) {
    af[0] += sc * sb8(v, 0); af[1] += sc * sb8(v, 1);
    af[2] += sc * sb8(v, 2); af[3] += sc * sb8(v, 3);
}

#define SPAN_CAP 1024

template<bool FINAL>
__global__ __launch_bounds__(256)
void sage_gather(const signed char* __restrict__ Gq, const float* __restrict__ Gsc,
                 const ushort* __restrict__ S, const float* __restrict__ bias,
                 const float* __restrict__ mask,
                 const int* __restrict__ row_ptr, const int* __restrict__ deg,
                 const int* __restrict__ esrc,
                 void* __restrict__ outv, int n) {
    constexpr int OUTW = FINAL ? 64 : 128;
    __shared__ int   idx_s[SPAN_CAP];
    __shared__ float sc_s[SPAN_CAP];

    const int tid  = threadIdx.x;
    const int lane = tid & 63;
    const int wave = tid >> 6;     // 0..3
    const int qw   = lane >> 4;
    const int l16  = lane & 15;
    const int base = blockIdx.x * 32;

    const int last   = min(base + 31, n - 1);
    const int span_s = row_ptr[base];
    const int span_e = row_ptr[last] + deg[last];
    const int len    = span_e - span_s;
    const bool staged = (len <= SPAN_CAP);
    if (staged) {
        for (int i = tid; i < len; i += 256) {
            int s_ = esrc[span_s + i];
            idx_s[i] = s_;
            sc_s[i] = Gsc[s_];
        }
    }
    __syncthreads();

#pragma unroll
    for (int j = 0; j < 2; ++j) {
        const int node = base + (wave * 4 + qw) * 2 + j;
        if (node >= n) continue;
        const int d = deg[node];
        const float inv = 1.f / fmaxf((float)d, 1.f);

        float af[8] = {0.f, 0.f, 0.f, 0.f, 0.f, 0.f, 0.f, 0.f};
        if (!FINAL) {
            const signed char* __restrict__ gp = Gq + l16 * 8;
            if (staged) {
                int i = row_ptr[node] - span_s, e = i + d;
                for (; i + 7 < e; i += 8) {          // 8 x 128B rows in flight
                    uint2 v[8]; float c[8];
#pragma unroll
                    for (int k = 0; k < 8; ++k) {
                        int ns = idx_s[i + k];
                        v[k] = *(const uint2*)&gp[(size_t)ns * 128];
                        c[k] = sc_s[i + k];
                    }
#pragma unroll
                    for (int k = 0; k < 8; ++k) acc8(af, v[k], c[k]);
                }
                for (; i < e; ++i) {
                    int ns = idx_s[i];
                    acc8(af, *(const uint2*)&gp[(size_t)ns * 128], sc_s[i]);
                }
            } else {
                int i = row_ptr[node], e = i + d;
                for (; i < e; ++i) {
                    int ns = esrc[i];
                    acc8(af, *(const uint2*)&gp[(size_t)ns * 128], Gsc[ns]);
                }
            }
            const int col0 = l16 * 8;
            uint4 sv = *(const uint4*)&S[(size_t)node * 128 + col0];
            float4 b0 = *(const float4*)&bias[col0];
            float4 b1 = *(const float4*)&bias[col0 + 4];
            float z[8];
            z[0] = bf2f(sv.x & 0xffffu) + af[0] * inv + b0.x;
            z[1] = bf2f(sv.x >> 16)     + af[1] * inv + b0.y;
            z[2] = bf2f(sv.y & 0xffffu) + af[2] * inv + b0.z;
            z[3] = bf2f(sv.y >> 16)     + af[3] * inv + b0.w;
            z[4] = bf2f(sv.z & 0xffffu) + af[4] * inv + b1.x;
            z[5] = bf2f(sv.z >> 16)     + af[5] * inv + b1.y;
            z[6] = bf2f(sv.w & 0xffffu) + af[6] * inv + b1.z;
            z[7] = bf2f(sv.w >> 16)     + af[7] * inv + b1.w;
            float4 m0 = *(const float4*)&mask[(size_t)node * 128 + col0];
            float4 m1 = *(const float4*)&mask[(size_t)node * 128 + col0 + 4];
            z[0] = fmaxf(z[0], 0.f) * m0.x; z[1] = fmaxf(z[1], 0.f) * m0.y;
            z[2] = fmaxf(z[2], 0.f) * m0.z; z[3] = fmaxf(z[3], 0.f) * m0.w;
            z[4] = fmaxf(z[4], 0.f) * m1.x; z[5] = fmaxf(z[5], 0.f) * m1.y;
            z[6] = fmaxf(z[6], 0.f) * m1.z; z[7] = fmaxf(z[7], 0.f) * m1.w;
            uint4 pk;
            pk.x = (uint)f2bf(z[0]) | ((uint)f2bf(z[1]) << 16);
            pk.y = (uint)f2bf(z[2]) | ((uint)f2bf(z[3]) << 16);
            pk.z = (uint)f2bf(z[4]) | ((uint)f2bf(z[5]) << 16);
            pk.w = (uint)f2bf(z[6]) | ((uint)f2bf(z[7]) << 16);
            *(uint4*)&((ushort*)outv)[(size_t)node * 128 + col0] = pk;
        } else {
            const signed char* __restrict__ gp = Gq + l16 * 4;
            if (staged) {
                int i = row_ptr[node] - span_s, e = i + d;
                for (; i + 7 < e; i += 8) {
                    uint v[8]; float c[8];
#pragma unroll
                    for (int k = 0; k < 8; ++k) {
                        int ns = idx_s[i + k];
                        v[k] = *(const uint*)&gp[(size_t)ns * 64];
                        c[k] = sc_s[i + k];
                    }
#pragma unroll
                    for (int k = 0; k < 8; ++k) acc4(af, v[k], c[k]);
                }
                for (; i < e; ++i) {
                    int ns = idx_s[i];
                    acc4(af, *(const uint*)&gp[(size_t)ns * 64], sc_s[i]);
                }
            } else {
                int i = row_ptr[node], e = i + d;
                for (; i < e; ++i) {
                    int ns = esrc[i];
                    acc4(af, *(const uint*)&gp[(size_t)ns * 64], Gsc[ns]);
                }
            }
            const int col0 = l16 * 4;
            uint2 sv = *(const uint2*)&S[(size_t)node * 64 + col0];
            float4 b0 = *(const float4*)&bias[col0];
            float4 z;
            z.x = bf2f(sv.x & 0xffffu) + af[0] * inv + b0.x;
            z.y = bf2f(sv.x >> 16)     + af[1] * inv + b0.y;
            z.z = bf2f(sv.y & 0xffffu) + af[2] * inv + b0.z;
            z.w = bf2f(sv.y >> 16)     + af[3] * inv + b0.w;
            *(float4*)&((float*)outv)[(size_t)node * 64 + col0] = z;
        }
    }
}

// ---------------------------------------------------------------------------
extern "C" void kernel_launch(void* const* d_in, const int* in_sizes, int n_in,
                              void* d_out, int out_size, void* d_ws, size_t ws_size,
                              hipStream_t stream) {
    const float* x   = (const float*)d_in[0];
    const int*   src = (const int*)d_in[1];
    const int*   dst = (const int*)d_in[2];
    const float* Ws1 = (const float*)d_in[3];
    const float* Wn1 = (const float*)d_in[4];
    const float* b1  = (const float*)d_in[5];
    const float* Ws2 = (const float*)d_in[6];
    const float* Wn2 = (const float*)d_in[7];
    const float* b2  = (const float*)d_in[8];
    const float* Ws3 = (const float*)d_in[9];
    const float* Wn3 = (const float*)d_in[10];
    const float* b3  = (const float*)d_in[11];
    const float* mask1 = (const float*)d_in[12];
    const float* mask2 = (const float*)d_in[13];
    float* out = (float*)d_out;

    const int N = in_sizes[0] / DIN;
    const int E = in_sizes[1];
    const int nbkt = (N + 255) >> 8;            // 196 for N=50000 (<=256)

    // Workspace layout
    char* ws = (char*)d_ws;
    int* bkt_cur  = (int*)ws;                   // 256
    int* row_ptr  = bkt_cur + 256;              // N
    int* deg      = row_ptr + N;                // N
    int* esrc     = deg + N;                    // nbkt*CAPB
    size_t off = ((size_t)(256 + 2 * N + nbkt * CAPB) * sizeof(int) + 255) & ~(size_t)255;
    uint* pairs  = (uint*)(ws + off);    off += (size_t)nbkt * CAPB * 4;
    ushort* xb   = (ushort*)(ws + off);  off += (size_t)N * 128 * 2;
    ushort* h1b  = (ushort*)(ws + off);  off += (size_t)N * 128 * 2;
    ushort* h2b  = (ushort*)(ws + off);  off += (size_t)N * 128 * 2;
    ushort* S    = (ushort*)(ws + off);  off += (size_t)N * 128 * 2;
    signed char* Gq = (signed char*)(ws + off); off += (size_t)N * 128;
    float* Gsc   = (float*)(ws + off);   off += (size_t)N * 4;
    ushort* Wst1 = (ushort*)(ws + off);  off += 128 * 128 * 2;
    ushort* Wnt1 = (ushort*)(ws + off);  off += 128 * 128 * 2;
    ushort* Wst2 = (ushort*)(ws + off);  off += 128 * 128 * 2;
    ushort* Wnt2 = (ushort*)(ws + off);  off += 128 * 128 * 2;
    ushort* Wst3 = (ushort*)(ws + off);  off += 64 * 128 * 2;
    ushort* Wnt3 = (ushort*)(ws + off);  off += 64 * 128 * 2;

    const int n4 = N * 128 / 4;
    const int cvtB = (n4 + 255) / 256;
    const int fillB = (E + EB - 1) / EB;        // 49

    // --- One prep dispatch: bucket fill + cvt + weight transposes ---
    hipMemsetAsync(bkt_cur, 0, 256 * sizeof(int), stream);
    megaprep<<<fillB + cvtB + 4 * 64 + 2 * 32, 256, 0, stream>>>(
        src, dst, E, fillB, bkt_cur, pairs,
        x, xb, n4, cvtB,
        Ws1, Wn1, Ws2, Wn2, Ws3, Wn3,
        Wst1, Wnt1, Wst2, Wnt2, Wst3, Wnt3);

    // --- CSR within buckets ---
    bucket_csr<<<nbkt, 256, 0, stream>>>(pairs, bkt_cur, row_ptr, deg, esrc, N, nbkt);

    const int gemmB = (N + 63) / 64;
    const int gathB = (N + 31) / 32;

    // --- Layer 1 ---
    sage_gemm<128><<<gemmB, 256, 0, stream>>>(xb, Wst1, Wnt1, S, Gq, Gsc, N);
    sage_gather<false><<<gathB, 256, 0, stream>>>(Gq, Gsc, S, b1, mask1, row_ptr, deg, esrc, h1b, N);
    // --- Layer 2 ---
    sage_gemm<128><<<gemmB, 256, 0, stream>>>(h1b, Wst2, Wnt2, S, Gq, Gsc, N);
    sage_gather<false><<<gathB, 256, 0, stream>>>(Gq, Gsc, S, b2, mask2, row_ptr, deg, esrc, h2b, N);
    // --- Layer 3 ---
    sage_gemm<64><<<gemmB, 256, 0, stream>>>(h2b, Wst3, Wnt3, S, Gq, Gsc, N);
    sage_gather<true><<<gathB, 256, 0, stream>>>(Gq, Gsc, S, b3, nullptr, row_ptr, deg, esrc, out, N);
}